// Round 2
// baseline (438.382 us; speedup 1.0000x reference)
//
#include <hip/hip_runtime.h>
#include <hip/hip_bf16.h>
#include <math.h>

// Problem: B=32, L=2048, E=512, Q=512, K=E+Q=1024, M=B*L=65536
// out = [applied (32*512 f32), weights (32*2048 f32)]
//
// v3 design (this round):
//  - BK 64->32: LDS 32 KB/block -> 4 blocks/CU resident (16 waves/CU, 4/SIMD).
//    Barrier drains overlap across blocks (the m114 mechanism round-1 lacked).
//  - 64-B LDS rows need a new swizzle: 16-B slot s of row r stored at
//    s ^ ((r>>1)&3). Frag reads land 2-way/bank (free); Wsw pre-permutation
//    updated so global_load_lds keeps a LINEAR dest (both-sides-or-neither).
//  - softmax stats hoisted to a 32-block kernel (identical reduction order ->
//    bit-identical weights); apply is now a pure stream reading w directly.

typedef __attribute__((ext_vector_type(8))) short bf16x8;
typedef __attribute__((ext_vector_type(4))) float f32x4;

#define BDIM 32
#define LDIM 2048
#define EDIM 512
#define QDIM 512
#define KDIM 1024
#define MDIM (BDIM * LDIM)

#define BM 128
#define BN 128
#define BK 32
#define NSTEPS (KDIM / BK)   // 32

// pack two fp32 -> two bf16 (round-half-up == RNE except exact ties; ties have
// prob ~2^-16 on random data). 2 v_add + 1 v_perm per 2 elements.
__device__ __forceinline__ unsigned int pack2bf(float lo, float hi) {
    unsigned int a = __builtin_bit_cast(unsigned int, lo) + 0x8000u;
    unsigned int b = __builtin_bit_cast(unsigned int, hi) + 0x8000u;
    return __builtin_amdgcn_perm(b, a, 0x07060302);
}

// ---------------------------------------------------------------------------
// W (512x1024 f32 row-major) -> bf16, pre-permuted so that a LINEAR
// global_load_lds fill produces the slot-swizzled LDS layout:
//   LDS row r (64 B), storage slot t holds logical slot t ^ ((r>>1)&3).
// So Wsw[n], k-group g (32 cols), slot t <- W[n][g*32 + (t^((n>>1)&3))*8 ..+8]
// (n0 is a multiple of 128, so (n>>1)&3 == (r>>1)&3 for r = n - n0.)
__global__ __launch_bounds__(256) void convert_w_kernel(
    const float* __restrict__ W, unsigned short* __restrict__ Wsw)
{
    const int gid = blockIdx.x * 256 + threadIdx.x;   // 512 rows * 128 16B-units
    const int n   = gid >> 7;
    const int rem = gid & 127;                        // 32 kgroups * 4 slots
    const int g   = rem >> 2;
    const int t   = rem & 3;
    const int srcslot = t ^ ((n >> 1) & 3);
    const float* src = W + (size_t)n * KDIM + g * 32 + srcslot * 8;
    const float4 a = *(const float4*)(src);
    const float4 c = *(const float4*)(src + 4);
    uint4 o;
    o.x = pack2bf(a.x, a.y); o.y = pack2bf(a.z, a.w);
    o.z = pack2bf(c.x, c.y); o.w = pack2bf(c.z, c.w);
    *(uint4*)((char*)Wsw + (size_t)n * 2048 + g * 64 + t * 16) = o;
}

// ---------------------------------------------------------------------------
__device__ __forceinline__ void load_a(const float* __restrict__ emb,
                                       const float* __restrict__ query,
                                       int m0, int kstep, int arow, int acol,
                                       float4 (&r)[4])
{
    const int k0 = kstep * BK;
    const float* asrc = (k0 < QDIM) ? query : emb;
    const int koff = (k0 < QDIM) ? k0 : (k0 - QDIM);
    #pragma unroll
    for (int p = 0; p < 4; p++)
        r[p] = *(const float4*)(asrc + (size_t)(m0 + p * 32 + arow) * 512 + koff + acol);
}

__device__ __forceinline__ void write_a(unsigned short* buf, int arow, int acolb,
                                        int axor, const float4 (&r)[4])
{
    #pragma unroll
    for (int p = 0; p < 4; p++) {
        uint2 pk;
        pk.x = pack2bf(r[p].x, r[p].y);
        pk.y = pack2bf(r[p].z, r[p].w);
        *(uint2*)((char*)buf + (p * 32 + arow) * 64 + (acolb ^ axor)) = pk;
    }
}

__device__ __forceinline__ void gll_b(const unsigned short* __restrict__ Wsw,
                                      unsigned short* buf, int n0, int kstep,
                                      int brow0, int bslot, int wvoff)
{
    const size_t kb = (size_t)kstep * 64;
    #pragma unroll
    for (int q = 0; q < 2; q++) {
        const char* g = (const char*)Wsw + (size_t)(n0 + q * 64 + brow0) * 2048 + kb + bslot * 16;
        __builtin_amdgcn_global_load_lds(
            (const __attribute__((address_space(1))) void*)g,
            (__attribute__((address_space(3))) void*)((char*)buf + q * 4096 + wvoff),
            16, 0, 0);
    }
}

__device__ __forceinline__ void compute_step(const unsigned short* a_,
                                             const unsigned short* b_,
                                             int abase, int bbase,
                                             f32x4 (&acc)[4][4])
{
    __builtin_amdgcn_s_setprio(1);
    bf16x8 af[4], bfr[4];
    #pragma unroll
    for (int i = 0; i < 4; i++) af[i] = *(const bf16x8*)((const char*)a_ + abase + i * 1024);
    #pragma unroll
    for (int j = 0; j < 4; j++) bfr[j] = *(const bf16x8*)((const char*)b_ + bbase + j * 1024);
    #pragma unroll
    for (int i = 0; i < 4; i++)
        #pragma unroll
        for (int j = 0; j < 4; j++)
            acc[i][j] = __builtin_amdgcn_mfma_f32_16x16x32_bf16(af[i], bfr[j], acc[i][j], 0, 0, 0);
    __builtin_amdgcn_s_setprio(0);
}

__global__ __launch_bounds__(256, 4) void scores_kernel(
    const float* __restrict__ emb, const float* __restrict__ query,
    const unsigned short* __restrict__ Wsw, const float* __restrict__ b_attn,
    const float* __restrict__ v_w, float* __restrict__ scores)
{
    // dbuf: 4 x 8 KB = 32 KB -> 4 blocks/CU (16 waves)
    __shared__ __align__(16) unsigned short As[2][BM * BK];
    __shared__ __align__(16) unsigned short Bs[2][BN * BK];

    const int tid = threadIdx.x;
    const int bid = blockIdx.x;
    // XCD-aware: give each XCD whole mtile groups so the 4 ntile-sharers of
    // one A-tile hit the same 4MB L2.
    const int xcd = bid & 7;
    const int slot = bid >> 3;
    const int mtile = xcd * 64 + (slot >> 2);
    const int ntile = slot & 3;
    const int m0 = mtile * BM;
    const int n0 = ntile * BN;

    const int lane = tid & 63;
    const int wv = tid >> 6;
    const int wm = (wv >> 1) * 64;
    const int wn = (wv & 1) * 64;
    const int quad = lane >> 4;
    const int ln = lane & 15;

    // A staging: 4 passes of 32 rows; thread -> row p*32+(tid>>3), 4 floats.
    const int arow  = tid >> 3;
    const int acol  = (tid & 7) * 4;
    const int acolb = acol * 2;
    const int axor  = ((arow >> 1) & 3) << 4;   // row-invariant across p (p*32 % 8 == 0)

    // B gll: issue q fills LDS bytes [q*4096 + wv*1024 + lane*16];
    // row = q*64 + wv*16 + (lane>>2), storage slot = lane&3.
    const int brow0 = wv * 16 + (lane >> 2);
    const int bslot = lane & 3;
    const int wvoff = __builtin_amdgcn_readfirstlane(wv << 10);

    // frag read bases: row*64 + (quad*16 ^ ((ln>>1&3)<<4)); i advances 16 rows = 1024 B.
    const int fxor  = ((ln >> 1) & 3) << 4;
    const int abase = (wm + ln) * 64 + ((quad * 16) ^ fxor);
    const int bbase = (wn + ln) * 64 + ((quad * 16) ^ fxor);

    f32x4 acc[4][4];
    #pragma unroll
    for (int i = 0; i < 4; i++)
        #pragma unroll
        for (int j = 0; j < 4; j++)
            acc[i][j] = (f32x4){0.f, 0.f, 0.f, 0.f};

    float4 ra[4], rb[4];

    // prologue: buf0 <- step 0; prefetch step 1 into rb
    load_a(emb, query, m0, 0, arow, acol, ra);
    write_a(&As[0][0], arow, acolb, axor, ra);
    gll_b(Wsw, &Bs[0][0], n0, 0, brow0, bslot, wvoff);
    load_a(emb, query, m0, 1, arow, acol, rb);
    __syncthreads();

    for (int t = 0; t < NSTEPS; t += 2) {
        // even step t: stage t+1 into buf1, prefetch t+2, compute buf0 (= t)
        if (t < NSTEPS - 2) load_a(emb, query, m0, t + 2, arow, acol, ra);
        write_a(&As[1][0], arow, acolb, axor, rb);
        gll_b(Wsw, &Bs[1][0], n0, t + 1, brow0, bslot, wvoff);
        compute_step(&As[0][0], &Bs[0][0], abase, bbase, acc);
        __syncthreads();

        // odd step t+1: stage t+2 into buf0, prefetch t+3, compute buf1 (= t+1)
        if (t + 1 < NSTEPS - 1) {
            if (t + 1 < NSTEPS - 2) load_a(emb, query, m0, t + 3, arow, acol, rb);
            write_a(&As[0][0], arow, acolb, axor, ra);
            gll_b(Wsw, &Bs[0][0], n0, t + 2, brow0, bslot, wvoff);
        }
        compute_step(&As[1][0], &Bs[1][0], abase, bbase, acc);
        __syncthreads();
    }

    // ---- fused epilogue: sum_n tanh(x + b[n]) * v_w[n], reduce over 16 cols ----
    float bj[4], vj[4];
    #pragma unroll
    for (int j = 0; j < 4; j++) {
        const int n = n0 + wn + j * 16 + ln;
        bj[j] = b_attn[n];
        vj[j] = v_w[n];
    }
    #pragma unroll
    for (int i = 0; i < 4; i++) {
        #pragma unroll
        for (int r = 0; r < 4; r++) {
            float s = 0.f;
            #pragma unroll
            for (int j = 0; j < 4; j++)
                s += tanhf(acc[i][j][r] + bj[j]) * vj[j];
            #pragma unroll
            for (int off = 1; off < 16; off <<= 1)
                s += __shfl_xor(s, off, 64);
            if (ln == 0)
                atomicAdd(&scores[m0 + wm + i * 16 + quad * 4 + r], s);
        }
    }
}

// ---------------------------------------------------------------------------
// Softmax stats once per batch row (same reduction order as before ->
// bit-identical weights). Grid: 32 blocks x 256 thr.
__global__ __launch_bounds__(256) void softmax_stats_kernel(
    const float* __restrict__ scores, float* __restrict__ out_weights)
{
    const int b = blockIdx.x;
    const int tid = threadIdx.x;
    const float* srow = scores + (size_t)b * LDIM;
    __shared__ float red[4];

    float sv[8];
    #pragma unroll
    for (int t = 0; t < 8; t++) sv[t] = srow[tid + t * 256];

    float mx = sv[0];
    #pragma unroll
    for (int t = 1; t < 8; t++) mx = fmaxf(mx, sv[t]);
    #pragma unroll
    for (int off = 1; off < 64; off <<= 1) mx = fmaxf(mx, __shfl_xor(mx, off, 64));
    if ((tid & 63) == 0) red[tid >> 6] = mx;
    __syncthreads();
    mx = fmaxf(fmaxf(red[0], red[1]), fmaxf(red[2], red[3]));

    float sm = 0.f;
    #pragma unroll
    for (int t = 0; t < 8; t++) sm += expf(sv[t] - mx);
    #pragma unroll
    for (int off = 1; off < 64; off <<= 1) sm += __shfl_xor(sm, off, 64);
    __syncthreads();
    if ((tid & 63) == 0) red[tid >> 6] = sm;
    __syncthreads();
    sm = red[0] + red[1] + red[2] + red[3];
    const float inv = 1.f / sm;

    #pragma unroll
    for (int t = 0; t < 8; t++)
        out_weights[(size_t)b * LDIM + tid + t * 256] = expf(sv[t] - mx) * inv;
}

// Pure-stream weighted sum: w read directly from out_weights.
// Grid: 32 b x 32 chunks (64 rows) = 1024 blocks x 256 thr.
__global__ __launch_bounds__(256) void apply_kernel(
    const float* __restrict__ emb, const float* __restrict__ w,
    float* __restrict__ out_applied)
{
    const int b = blockIdx.x >> 5;
    const int chunk = blockIdx.x & 31;
    const int l0 = chunk * 64;
    const int tid = threadIdx.x;

    __shared__ float wls[64];
    __shared__ float partial[512];

    if (tid < 64) wls[tid] = w[(size_t)b * LDIM + l0 + tid];
    __syncthreads();

    const int half = tid >> 7;          // wave-uniform
    const int cg = tid & 127;           // column group of 4 floats
    float4 acc = {0.f, 0.f, 0.f, 0.f};
    const float* ebase = emb + ((size_t)b * LDIM + l0 + half) * EDIM + cg * 4;
    #pragma unroll 8
    for (int i = 0; i < 32; i++) {
        const float4 v = *(const float4*)(ebase + (size_t)2 * i * EDIM);
        const float ww = wls[half + 2 * i];
        acc.x += ww * v.x;
        acc.y += ww * v.y;
        acc.z += ww * v.z;
        acc.w += ww * v.w;
    }
    if (half == 1) *(float4*)&partial[cg * 4] = acc;
    __syncthreads();
    if (half == 0) {
        const float4 p = *(const float4*)&partial[cg * 4];
        float* dst = out_applied + (size_t)b * EDIM + cg * 4;
        atomicAdd(dst + 0, acc.x + p.x);
        atomicAdd(dst + 1, acc.y + p.y);
        atomicAdd(dst + 2, acc.z + p.z);
        atomicAdd(dst + 3, acc.w + p.w);
    }
}

extern "C" void kernel_launch(void* const* d_in, const int* in_sizes, int n_in,
                              void* d_out, int out_size, void* d_ws, size_t ws_size,
                              hipStream_t stream) {
    const float* emb    = (const float*)d_in[0];
    const float* query  = (const float*)d_in[1];
    const float* W      = (const float*)d_in[2];
    const float* b_attn = (const float*)d_in[3];
    const float* v_w    = (const float*)d_in[4];

    float* out     = (float*)d_out;
    float* applied = out;                 // 32*512 floats
    float* weights = out + BDIM * EDIM;   // 32*2048 floats

    float* scores  = (float*)d_ws;                                           // 256 KB
    unsigned short* Wsw = (unsigned short*)((char*)d_ws + (size_t)MDIM * 4); // 1 MB swizzled bf16 W

    hipMemsetAsync(scores, 0, (size_t)MDIM * sizeof(float), stream);
    hipMemsetAsync(applied, 0, (size_t)BDIM * EDIM * sizeof(float), stream);

    convert_w_kernel<<<256, 256, 0, stream>>>(W, Wsw);

    // grid = (M/BM) * (N/BN) = 512 * 4 = 2048 blocks
    scores_kernel<<<2048, 256, 0, stream>>>(emb, query, Wsw, b_attn, v_w, scores);

    softmax_stats_kernel<<<32, 256, 0, stream>>>(scores, weights);

    // grid = B * 32 chunks = 1024 blocks
    apply_kernel<<<1024, 256, 0, stream>>>(emb, weights, applied);
}

// Round 3
// 392.135 us; speedup vs baseline: 1.1179x; 1.1179x over previous
//
#include <hip/hip_runtime.h>
#include <hip/hip_bf16.h>
#include <math.h>

// Problem: B=32, L=2048, E=512, Q=512, K=E+Q=1024, M=B*L=65536
// out = [applied (32*512 f32), weights (32*2048 f32)]
//
// v4 design (this round):
//  - scores: R1 geometry (BM=BN=128, BK=64, 4 waves, dbuf LDS, 2 blocks/CU)
//    + T4 counted-vmcnt barriers: s_waitcnt vmcnt(8) lgkmcnt(0) + raw
//    s_barrier. Per-step vmem order is uniform (4 gll_b, then 8 A-loads), so
//    vmcnt(8) drains exactly the W staging and the 2-step-deep A prefetch
//    stays in flight ACROSS the barrier (this was R1's exposed stall).
//    Tail steps clamped to keep counts static.
//  - scores epilogue: LDS cross-wave reduce -> plain stores into 4 partial
//    buffers (no atomics, no scores memset); stats kernel sums them.
//  - apply: 2048 blocks (32-row chunks) pure stream.

typedef __attribute__((ext_vector_type(8))) short bf16x8;
typedef __attribute__((ext_vector_type(4))) float f32x4;

#define BDIM 32
#define LDIM 2048
#define EDIM 512
#define QDIM 512
#define KDIM 1024
#define MDIM (BDIM * LDIM)

#define BM 128
#define BN 128
#define BK 64
#define NSTEPS (KDIM / BK)   // 16

// Counted-vmcnt barrier: drain this step's 4 global_load_lds (and all LDS
// ops), keep the 8 A-prefetch loads in flight. Static count is valid because
// every loop body issues exactly [4 gll][8 A-loads] in this order.
#define BAR() do { \
    asm volatile("s_waitcnt vmcnt(8) lgkmcnt(0)" ::: "memory"); \
    __builtin_amdgcn_s_barrier(); \
    __builtin_amdgcn_sched_barrier(0); \
} while (0)

// pack two fp32 -> two bf16 (round-half-up == RNE except exact ties; ties have
// prob ~2^-16 on random data). 2 v_add + 1 v_perm per 2 elements.
__device__ __forceinline__ unsigned int pack2bf(float lo, float hi) {
    unsigned int a = __builtin_bit_cast(unsigned int, lo) + 0x8000u;
    unsigned int b = __builtin_bit_cast(unsigned int, hi) + 0x8000u;
    return __builtin_amdgcn_perm(b, a, 0x07060302);
}

// ---------------------------------------------------------------------------
// W (512x1024 f32 row-major) -> bf16 with per-row byte-XOR swizzle baked in
// (Wsw.byte[n][j] = bf16(W)[n].byte[j ^ ((n&7)<<4)]) so the GEMM fills LDS
// linearly with global_load_lds and reads conflict-free (R1-proven pair).
__global__ __launch_bounds__(256) void convert_w_kernel(
    const float* __restrict__ W, unsigned short* __restrict__ Wsw)
{
    const int gid = blockIdx.x * 256 + threadIdx.x;   // 512 rows * 128 16B-units
    const int n  = gid >> 7;
    const int jb = (gid & 127) * 16;                  // output byte offset in 2048B row
    const int sb = jb ^ ((n & 7) << 4);               // source byte offset (16B-granular XOR)
    const float* src = W + (size_t)n * KDIM + (sb >> 1); // bf16-byte off -> float off = sb/2
    const float4 a = *(const float4*)(src);
    const float4 c = *(const float4*)(src + 4);
    uint4 o;
    o.x = pack2bf(a.x, a.y); o.y = pack2bf(a.z, a.w);
    o.z = pack2bf(c.x, c.y); o.w = pack2bf(c.z, c.w);
    *(uint4*)((char*)Wsw + (size_t)n * 2048 + jb) = o;
}

// ---------------------------------------------------------------------------
__device__ __forceinline__ bf16x8 lds_frag(const unsigned short* buf, int row, int cb) {
    return *(const bf16x8*)((const char*)buf + row * 128 + (cb ^ ((row & 7) << 4)));
}

__device__ __forceinline__ void load_a(const float* __restrict__ emb,
                                       const float* __restrict__ query,
                                       int m0, int kstep, int arow, int acol,
                                       float4 (&r)[8])
{
    const int k0 = kstep * BK;
    const float* asrc = (k0 < QDIM) ? query : emb;
    const int koff = (k0 < QDIM) ? k0 : (k0 - QDIM);
    #pragma unroll
    for (int p = 0; p < 8; p++)
        r[p] = *(const float4*)(asrc + (size_t)(m0 + p * 16 + arow) * 512 + koff + acol);
}

__device__ __forceinline__ void write_a(unsigned short* buf, int arow, int acolb,
                                        int axor, const float4 (&r)[8])
{
    #pragma unroll
    for (int p = 0; p < 8; p++) {
        uint2 pk;
        pk.x = pack2bf(r[p].x, r[p].y);
        pk.y = pack2bf(r[p].z, r[p].w);
        *(uint2*)((char*)buf + (p * 16 + arow) * 128 + (acolb ^ axor)) = pk;
    }
}

__device__ __forceinline__ void gll_b(const unsigned short* __restrict__ Wsw,
                                      unsigned short* buf, int n0, int kstep,
                                      int brow, int bcb, int wvoff)
{
    const size_t kb = (size_t)kstep * (BK * 2);
    #pragma unroll
    for (int p = 0; p < 4; p++) {
        const char* g = (const char*)Wsw + (size_t)(n0 + p * 32 + brow) * 2048 + kb + bcb;
        __builtin_amdgcn_global_load_lds(
            (const __attribute__((address_space(1))) void*)g,
            (__attribute__((address_space(3))) void*)((char*)buf + p * 4096 + wvoff),
            16, 0, 0);
    }
}

__device__ __forceinline__ void compute_step(const unsigned short* a_,
                                             const unsigned short* b_,
                                             int wm, int wn, int ln, int quad,
                                             f32x4 (&acc)[4][4])
{
    __builtin_amdgcn_s_setprio(1);
    #pragma unroll
    for (int ks = 0; ks < 2; ks++) {
        bf16x8 af[4], bfr[4];
        #pragma unroll
        for (int i = 0; i < 4; i++) af[i] = lds_frag(a_, wm + i * 16 + ln, ks * 64 + quad * 16);
        #pragma unroll
        for (int j = 0; j < 4; j++) bfr[j] = lds_frag(b_, wn + j * 16 + ln, ks * 64 + quad * 16);
        #pragma unroll
        for (int i = 0; i < 4; i++)
            #pragma unroll
            for (int j = 0; j < 4; j++)
                acc[i][j] = __builtin_amdgcn_mfma_f32_16x16x32_bf16(af[i], bfr[j], acc[i][j], 0, 0, 0);
    }
    __builtin_amdgcn_s_setprio(0);
}

__global__ __launch_bounds__(256, 2) void scores_kernel(
    const float* __restrict__ emb, const float* __restrict__ query,
    const unsigned short* __restrict__ Wsw, const float* __restrict__ b_attn,
    const float* __restrict__ v_w, float* __restrict__ part)
{
    // dbuf: 4 x 16KB = 64 KB -> 2 blocks/CU (8 waves)
    __shared__ __align__(16) unsigned short As[2][BM * BK];
    __shared__ __align__(16) unsigned short Bs[2][BN * BK];

    const int tid = threadIdx.x;
    const int bid = blockIdx.x;
    // XCD-aware: give each XCD whole mtile groups so the 4 ntile-sharers of
    // one A-tile hit the same 4MB L2.
    const int xcd = bid & 7;
    const int slot = bid >> 3;
    const int mtile = xcd * 64 + (slot >> 2);
    const int ntile = slot & 3;
    const int m0 = mtile * BM;
    const int n0 = ntile * BN;

    const int lane = tid & 63;
    const int wv = tid >> 6;
    const int wm = (wv >> 1) * 64;
    const int wn = (wv & 1) * 64;
    const int quad = lane >> 4;
    const int ln = lane & 15;

    // A staging: 8 passes of 16 rows; thread -> row p*16+(tid>>4), 4 floats.
    const int arow  = tid >> 4;
    const int acol  = (tid & 15) * 4;
    const int acolb = acol * 2;
    const int axor  = (arow & 7) << 4;

    // B gll: issue p fills LDS bytes [p*4096 + tid*16]; row = p*32 + tid/8.
    const int brow = tid >> 3;
    const int bcb  = (tid & 7) * 16;
    const int wvoff = __builtin_amdgcn_readfirstlane((tid >> 6) << 10);

    f32x4 acc[4][4];
    #pragma unroll
    for (int i = 0; i < 4; i++)
        #pragma unroll
        for (int j = 0; j < 4; j++)
            acc[i][j] = (f32x4){0.f, 0.f, 0.f, 0.f};

    float4 ra[8], rb[8];

    // prologue: stage step 0 into buf0; prefetch step 1 into rb.
    // vmem issue order: [ra 8][gll 4][rb 8] -> vmcnt(8) drains gll (rb stays).
    load_a(emb, query, m0, 0, arow, acol, ra);
    gll_b(Wsw, &Bs[0][0], n0, 0, brow, bcb, wvoff);
    load_a(emb, query, m0, 1, arow, acol, rb);
    write_a(&As[0][0], arow, acolb, axor, ra);
    BAR();

    for (int t = 0; t < NSTEPS; t += 2) {
        // even step: compute data t from buf0; stage t+1 -> buf1; prefetch t+2.
        gll_b(Wsw, &Bs[1][0], n0, t + 1, brow, bcb, wvoff);
        {
            const int kpre = (t + 2 < NSTEPS) ? t + 2 : NSTEPS - 1;   // clamp: uniform counts
            load_a(emb, query, m0, kpre, arow, acol, ra);
        }
        write_a(&As[1][0], arow, acolb, axor, rb);
        compute_step(&As[0][0], &Bs[0][0], wm, wn, ln, quad, acc);
        BAR();

        // odd step: compute data t+1 from buf1; stage t+2 -> buf0; prefetch t+3.
        {
            const int kst = (t + 2 < NSTEPS) ? t + 2 : NSTEPS - 1;
            gll_b(Wsw, &Bs[0][0], n0, kst, brow, bcb, wvoff);
            const int kpre = (t + 3 < NSTEPS) ? t + 3 : NSTEPS - 1;
            load_a(emb, query, m0, kpre, arow, acol, rb);
            write_a(&As[0][0], arow, acolb, axor, ra);
        }
        compute_step(&As[1][0], &Bs[1][0], wm, wn, ln, quad, acc);
        BAR();
    }

    // ---- fused epilogue: sum_n tanh(x + b[n]) * v_w[n] ----
    // Per-wave 16-lane shfl reduce, then LDS cross-wave (wn-half) reduce,
    // then ONE plain store per (ntile, m) into the partials buffer.
    float bj[4], vj[4];
    #pragma unroll
    for (int j = 0; j < 4; j++) {
        const int n = n0 + wn + j * 16 + ln;
        bj[j] = b_attn[n];
        vj[j] = v_w[n];
    }
    float* redbuf = (float*)&As[0][0];   // LDS reuse: 256 floats
    const int half = wn >> 6;
    #pragma unroll
    for (int i = 0; i < 4; i++) {
        #pragma unroll
        for (int r = 0; r < 4; r++) {
            float s = 0.f;
            #pragma unroll
            for (int j = 0; j < 4; j++)
                s += tanhf(acc[i][j][r] + bj[j]) * vj[j];
            #pragma unroll
            for (int off = 1; off < 16; off <<= 1)
                s += __shfl_xor(s, off, 64);
            if (ln == 0)
                redbuf[half * 128 + wm + i * 16 + quad * 4 + r] = s;
        }
    }
    __syncthreads();
    if (tid < 128)
        part[(size_t)ntile * MDIM + m0 + tid] = redbuf[tid] + redbuf[128 + tid];
}

// ---------------------------------------------------------------------------
// Softmax stats once per batch row; sums the 4 ntile partials inline.
// Grid: 32 blocks x 256 thr.
__global__ __launch_bounds__(256) void softmax_stats_kernel(
    const float* __restrict__ part, float* __restrict__ out_weights)
{
    const int b = blockIdx.x;
    const int tid = threadIdx.x;
    __shared__ float red[4];

    float sv[8];
    #pragma unroll
    for (int t = 0; t < 8; t++) {
        const size_t idx = (size_t)b * LDIM + tid + t * 256;
        float s = part[idx];
        #pragma unroll
        for (int j = 1; j < 4; j++) s += part[(size_t)j * MDIM + idx];
        sv[t] = s;
    }

    float mx = sv[0];
    #pragma unroll
    for (int t = 1; t < 8; t++) mx = fmaxf(mx, sv[t]);
    #pragma unroll
    for (int off = 1; off < 64; off <<= 1) mx = fmaxf(mx, __shfl_xor(mx, off, 64));
    if ((tid & 63) == 0) red[tid >> 6] = mx;
    __syncthreads();
    mx = fmaxf(fmaxf(red[0], red[1]), fmaxf(red[2], red[3]));

    float sm = 0.f;
    #pragma unroll
    for (int t = 0; t < 8; t++) sm += expf(sv[t] - mx);
    #pragma unroll
    for (int off = 1; off < 64; off <<= 1) sm += __shfl_xor(sm, off, 64);
    __syncthreads();
    if ((tid & 63) == 0) red[tid >> 6] = sm;
    __syncthreads();
    sm = red[0] + red[1] + red[2] + red[3];
    const float inv = 1.f / sm;

    #pragma unroll
    for (int t = 0; t < 8; t++)
        out_weights[(size_t)b * LDIM + tid + t * 256] = expf(sv[t] - mx) * inv;
}

// Pure-stream weighted sum: w read directly from out_weights.
// Grid: 32 b x 64 chunks (32 rows) = 2048 blocks x 256 thr.
__global__ __launch_bounds__(256) void apply_kernel(
    const float* __restrict__ emb, const float* __restrict__ w,
    float* __restrict__ out_applied)
{
    const int b = blockIdx.x >> 6;
    const int chunk = blockIdx.x & 63;
    const int l0 = chunk * 32;
    const int tid = threadIdx.x;

    __shared__ float wls[32];
    __shared__ float partial[512];

    if (tid < 32) wls[tid] = w[(size_t)b * LDIM + l0 + tid];
    __syncthreads();

    const int half = tid >> 7;          // wave-uniform
    const int cg = tid & 127;           // column group of 4 floats
    float4 acc = {0.f, 0.f, 0.f, 0.f};
    const float* ebase = emb + ((size_t)b * LDIM + l0 + half) * EDIM + cg * 4;
    #pragma unroll
    for (int i = 0; i < 16; i++) {
        const float4 v = *(const float4*)(ebase + (size_t)2 * i * EDIM);
        const float ww = wls[half + 2 * i];
        acc.x += ww * v.x;
        acc.y += ww * v.y;
        acc.z += ww * v.z;
        acc.w += ww * v.w;
    }
    if (half == 1) *(float4*)&partial[cg * 4] = acc;
    __syncthreads();
    if (half == 0) {
        const float4 p = *(const float4*)&partial[cg * 4];
        float* dst = out_applied + (size_t)b * EDIM + cg * 4;
        atomicAdd(dst + 0, acc.x + p.x);
        atomicAdd(dst + 1, acc.y + p.y);
        atomicAdd(dst + 2, acc.z + p.z);
        atomicAdd(dst + 3, acc.w + p.w);
    }
}

extern "C" void kernel_launch(void* const* d_in, const int* in_sizes, int n_in,
                              void* d_out, int out_size, void* d_ws, size_t ws_size,
                              hipStream_t stream) {
    const float* emb    = (const float*)d_in[0];
    const float* query  = (const float*)d_in[1];
    const float* W      = (const float*)d_in[2];
    const float* b_attn = (const float*)d_in[3];
    const float* v_w    = (const float*)d_in[4];

    float* out     = (float*)d_out;
    float* applied = out;                 // 32*512 floats
    float* weights = out + BDIM * EDIM;   // 32*2048 floats

    float* part = (float*)d_ws;                                              // 4*MDIM f32 = 1 MB
    unsigned short* Wsw = (unsigned short*)((char*)d_ws + (size_t)4 * MDIM * 4); // 1 MB swizzled bf16 W

    hipMemsetAsync(applied, 0, (size_t)BDIM * EDIM * sizeof(float), stream);

    convert_w_kernel<<<256, 256, 0, stream>>>(W, Wsw);

    // grid = (M/BM) * (N/BN) = 512 * 4 = 2048 blocks
    scores_kernel<<<2048, 256, 0, stream>>>(emb, query, Wsw, b_attn, v_w, part);

    softmax_stats_kernel<<<32, 256, 0, stream>>>(part, weights);

    // grid = B * 64 chunks = 2048 blocks
    apply_kernel<<<2048, 256, 0, stream>>>(emb, weights, applied);
}